// Round 9
// baseline (151.877 us; speedup 1.0000x reference)
//
#include <hip/hip_runtime.h>
#include <math.h>

#define NS 1024   // speakers
#define NU 64     // utterances per speaker
#define NE 256    // embedding dim

typedef __attribute__((ext_vector_type(4))) float f32x4;
typedef __attribute__((ext_vector_type(16))) float f32x16;
typedef long i64x2 __attribute__((ext_vector_type(2)));  // 16B fragment pair

// pack 4 floats -> 4 fp8 e4m3 bytes (HW cvt, OCP on gfx950)
__device__ static inline unsigned int pk4_fp8(float a, float b, float c,
                                              float d) {
  int r = 0;
  r = __builtin_amdgcn_cvt_pk_fp8_f32(a, b, r, false);  // bytes 0,1
  r = __builtin_amdgcn_cvt_pk_fp8_f32(c, d, r, true);   // bytes 2,3
  return (unsigned int)r;
}

// ws layout (bytes):
//   Cb     @ 0     : 1024 cols x 256 k fp8 (256 KB), 32x32-B-frag-permuted
//   pmaxG  @ 256K  : 65536 u32 (256 KB)  float bits of max p per row
//   ssumG  @ 512K  : 65536 f32 (256 KB)  sum of exp(l-M0) per row
//   pdiagG @ 768K  : 65536 f32 (256 KB)  exp(l_gt-M0) per row
//   normsum@ 1024K : 1024 f32 (4 KB)
//   Ab     @ 1056K : 65536 rows x 256 k fp8 (16 MB), 32x32-A-frag-permuted
//
// NOTE: embeds rows are L2-normalized by the reference setup -> ||e||^2 = 1.
//
// v9 fragment layout for mfma_f32_32x32x16_fp8_fp8 (A and B identical):
// 32-wide tile rt (=row>>5 or col>>5), k-step s (=k>>4, 0..15), lane l:
//   row/col = l&31, k-byte = s*16 + (l>>5)*8 + j (j=0..7 within the u64).
// Paired for dwordx4: i64x2 at [(rt*8 + (s>>1))*64 + l] = {s even, s odd}.

__global__ __launch_bounds__(256) void centroid_kernel(
    const float* __restrict__ embeds, unsigned int* __restrict__ Cb,
    unsigned long long* __restrict__ Ab, float* __restrict__ normsum,
    float* __restrict__ ssumG, unsigned int* __restrict__ pmaxG,
    float* __restrict__ out) {
  int k = blockIdx.x;   // speaker
  int t = threadIdx.x;
  // zero the per-row accumulators (ws re-poisoned every launch)
  if (t < 64) {
    ssumG[k * 64 + t] = 0.f;
    pmaxG[k * 64 + t] = 0u;
  }
  int wave = t >> 6, e4 = t & 63;

  // ---- phase A: per-speaker sum -> normalized centroid (Cb, fp8) ----
  const float4* base =
      (const float4*)(embeds + (size_t)k * NU * NE) + wave * 16 * 64 + e4;
  float4 s = {0.f, 0.f, 0.f, 0.f};
#pragma unroll
  for (int i = 0; i < 16; ++i) {
    float4 v = base[i * 64];
    s.x += v.x; s.y += v.y; s.z += v.z; s.w += v.w;
  }
  __shared__ float4 ps[4][64];
  ps[wave][e4] = s;
  __syncthreads();
  if (t < 64) {
    float4 a = ps[0][t], b = ps[1][t], c = ps[2][t], d = ps[3][t];
    float4 s4;
    s4.x = a.x + b.x + c.x + d.x;
    s4.y = a.y + b.y + c.y + d.y;
    s4.z = a.z + b.z + c.z + d.z;
    s4.w = a.w + b.w + c.w + d.w;
    float sq = s4.x * s4.x + s4.y * s4.y + s4.z * s4.z + s4.w * s4.w;
#pragma unroll
    for (int off = 32; off; off >>= 1) sq += __shfl_xor(sq, off, 64);
    float nrm = sqrtf(sq);
    float inv = 1.f / nrm;
    unsigned int v = pk4_fp8(s4.x * inv, s4.y * inv, s4.z * inv, s4.w * inv);
    // thread t holds centroid bytes kb=4t..4t+3.
    // 32x32-B layout: s=t>>2; lane=(k&31)+32*((t>>1)&1); sp=t>>3;
    // u32 idx = (k>>5)*2048 + sp*256 + lane*4 + (s&1)*2 + (t&1)
    int lane_ = (k & 31) + 32 * ((t >> 1) & 1);
    int idx = (k >> 5) * 2048 + (t >> 3) * 256 + lane_ * 4 +
              (((t >> 2) & 1) << 1) + (t & 1);
    Cb[idx] = v;
    if (t == 0) {
      normsum[k] = nrm;
      if (k == 0) { out[0] = 0.f; out[1] = 0.f; }
    }
  }

  // ---- phase B: fp8 A-fragments for this speaker's 64 rows (L1/L2 warm) ----
  {
    int tt = t >> 7;        // row tile 0..1 (32 rows) within speaker
    int l = t & 63;
    int hp = (t >> 6) & 1;  // sp half: sp in [hp*4, hp*4+4)
    int row = k * 64 + tt * 32 + (l & 31);
    int kbase = (l >> 5) * 8;
    const float* rowp = embeds + (size_t)row * NE;
    i64x2* Ab2 = (i64x2*)Ab;
    size_t rt = (size_t)k * 2 + tt;
#pragma unroll
    for (int i = 0; i < 4; ++i) {
      int sp = hp * 4 + i;
      unsigned long long u[2];
#pragma unroll
      for (int half = 0; half < 2; ++half) {
        int sI = 2 * sp + half;
        int k0 = sI * 16 + kbase;
        float4 x = *(const float4*)(rowp + k0);
        float4 y = *(const float4*)(rowp + k0 + 4);
        unsigned int lo = pk4_fp8(x.x, x.y, x.z, x.w);
        unsigned int hi = pk4_fp8(y.x, y.y, y.z, y.w);
        u[half] = ((unsigned long long)hi << 32) | lo;
      }
      i64x2 v;
      v.x = (long)u[0];
      v.y = (long)u[1];
      Ab2[(rt * 8 + sp) * 64 + l] = v;
    }
  }
}

// Barrier-free fp8 main v9. r0-r8 evidence: ~44us invariant vs occupancy,
// B-path, prefetch depth => the wall is the instruction stream itself:
// VALU-busy (~53K cyc/CU, OCML exp2f bloat + 75 insts/tile) + MFMA issue
// (2.1M 16x16 ops) run near-serial and sum to the 44us. v9 halves both:
// 32x32x16 fp8 MFMA (1.05M ops, 2495-TF ceiling -> 13.8us pipe floor) and
// raw v_exp_f32 via __builtin_amdgcn_exp2f (1 inst vs ~8; exponents in
// [-35,0] need no range fixup). v3 skeleton otherwise: private B loads,
// in-tile refill, ping-pong epilogue, no setprio, no launch-bounds pin.
__global__ __launch_bounds__(256) void main_kernel(
    const long* __restrict__ Ab, const long* __restrict__ Cb,
    const float* __restrict__ normsum, const float* __restrict__ wp,
    const float* __restrict__ bp, float* __restrict__ ssumG,
    unsigned int* __restrict__ pmaxG, float* __restrict__ pdiagG) {
  int t = threadIdx.x;
  int wave = t >> 6, lane = t & 63;
  int hi = lane >> 5;
  int b = blockIdx.x;               // 0..1023
  int rg = b >> 1;                  // row group 0..511 (128 rows each)
  int h = b & 1;                    // column half: cols [h*512, +512)
  int jspk = rg * 2 + (wave >> 1);  // this wave's speaker (diag column)
  int r0 = rg * 128 + wave * 32;    // global row base for this wave

  float w = *wp, bia = *bp;
  const float L2E = 1.4426950408889634f;
  float M0 = fabsf(w) + bia;        // >= any logit (cosines in [-1,1])
  float wl = w * L2E;               // p = 2^(d*wl + cl) = exp(l - M0)
  float cl = (bia - M0) * L2E;
  float ns = normsum[jspk];

  const i64x2* Av = (const i64x2*)Ab;
  const i64x2* Bv = (const i64x2*)Cb;
  int gt_base = h * 16;             // global 32-col tile base

  // ---- A fragments: 8 dwordx4 loads (32 rows x 256 k fp8) ----
  long af[16];
  {
    int rt = rg * 4 + wave;  // = r0 >> 5
#pragma unroll
    for (int sp = 0; sp < 8; ++sp) {
      i64x2 v = Av[(rt * 8 + sp) * 64 + lane];
      af[2 * sp] = v.x;
      af[2 * sp + 1] = v.y;
    }
  }

  // ---- per-lane softmax state: 16 rows (one col each) ----
  float ssum[16], pm[16];
#pragma unroll
  for (int i = 0; i < 16; ++i) {
    ssum[i] = 0.f;
    pm[i] = 0.f;  // p > 0 always
  }

  // B loads: 4 dwordx4 per K-half per 32-col tile
  auto loadBA = [&](i64x2 (&BF)[4], int ct) {  // sp 0..3 (k 0..127)
    int cb = (gt_base + ct) * 512 + lane;
#pragma unroll
    for (int sp = 0; sp < 4; ++sp) BF[sp] = Bv[cb + sp * 64];
  };
  auto loadBB = [&](i64x2 (&BF)[4], int ct) {  // sp 4..7 (k 128..255)
    int cb = (gt_base + ct) * 512 + lane + 256;
#pragma unroll
    for (int i = 0; i < 4; ++i) BF[i] = Bv[cb + i * 64];
  };

  // one 32-col tile: 16 MFMAs (single chain), refill B for tile nextT inside
  auto tile = [&](f32x16& ACC, i64x2 (&BA)[4], i64x2 (&BB)[4], int nextT) {
    f32x16 a;
#pragma unroll
    for (int i = 0; i < 16; ++i) a[i] = 0.f;
    int nt = nextT < 16 ? nextT : 15;  // clamped dup refill, never consumed
#pragma unroll
    for (int sp = 0; sp < 4; ++sp) {
      a = __builtin_amdgcn_mfma_f32_32x32x16_fp8_fp8(af[2 * sp], BA[sp].x, a,
                                                     0, 0, 0);
      a = __builtin_amdgcn_mfma_f32_32x32x16_fp8_fp8(af[2 * sp + 1], BA[sp].y,
                                                     a, 0, 0, 0);
    }
    loadBA(BA, nt);
#pragma unroll
    for (int sp = 0; sp < 4; ++sp) {
      a = __builtin_amdgcn_mfma_f32_32x32x16_fp8_fp8(af[8 + 2 * sp], BB[sp].x,
                                                     a, 0, 0, 0);
      a = __builtin_amdgcn_mfma_f32_32x32x16_fp8_fp8(af[9 + 2 * sp], BB[sp].y,
                                                     a, 0, 0, 0);
    }
    loadBB(BB, nt);
    ACC = a;
  };

  // softmax epilogue for 32-col tile T. C/D layout (verified m74/m101):
  // col = lane&31, row = (reg&3) + 8*(reg>>2) + 4*(lane>>5).
  auto epilogue = [&](f32x16& ACC, int T) {
    int gt = gt_base + T;
    bool diagstep = ((jspk >> 5) == gt);  // wave-uniform
    f32x16 a = ACC;
    if (diagstep && (lane & 31) == (jspk & 31)) {
#pragma unroll
      for (int i = 0; i < 16; ++i) {
        float Sv = a[i] * ns;  // e . sum_j  (||e||^2 = 1 by construction)
        float den = fmaxf(fmaf(ns, ns, 1.f) - 2.f * Sv, 1e-30f);
        float val = (Sv - 1.f) * __frsqrt_rn(den);
        float pd = __builtin_amdgcn_exp2f(fmaf(val, wl, cl));  // == epilogue p
        pdiagG[r0 + (i & 3) + 8 * (i >> 2) + 4 * hi] = pd;
        a[i] = val;
      }
    }
#pragma unroll
    for (int i = 0; i < 16; ++i) {
      float p = __builtin_amdgcn_exp2f(fmaf(a[i], wl, cl));  // exp(l - M0)
      ssum[i] += p;
      pm[i] = fmaxf(pm[i], p);
    }
  };

  // ---- pipelined loop over this half's 16 col-tiles, ping-pong epilogue ----
  i64x2 BA[4], BB[4];
  f32x16 accA, accB;
  loadBA(BA, 0);
  loadBB(BB, 0);
  tile(accA, BA, BB, 1);  // tile 0, refill -> 1
#pragma unroll 1
  for (int T = 1; T < 15; T += 2) {
    tile(accB, BA, BB, T + 1);  // tile T, refill -> T+1
    epilogue(accA, T - 1);
    tile(accA, BA, BB, T + 2);  // tile T+1, refill -> T+2
    epilogue(accB, T);
  }
  tile(accB, BA, BB, 16);  // tile 15 (refill clamped/dup)
  epilogue(accA, 14);
  epilogue(accB, 15);

  // ---- cross-lane reduce over the 32 cols (lanes within each half) ----
#pragma unroll
  for (int i = 0; i < 16; ++i) {
    float s = ssum[i];
    s += __shfl_xor(s, 1, 64);
    s += __shfl_xor(s, 2, 64);
    s += __shfl_xor(s, 4, 64);
    s += __shfl_xor(s, 8, 64);
    s += __shfl_xor(s, 16, 64);
    float m = pm[i];
    m = fmaxf(m, __shfl_xor(m, 1, 64));
    m = fmaxf(m, __shfl_xor(m, 2, 64));
    m = fmaxf(m, __shfl_xor(m, 4, 64));
    m = fmaxf(m, __shfl_xor(m, 8, 64));
    m = fmaxf(m, __shfl_xor(m, 16, 64));
    if ((lane & 31) == 0) {
      int row = r0 + (i & 3) + 8 * (i >> 2) + 4 * hi;
      atomicAdd(&ssumG[row], s);
      atomicMax(&pmaxG[row], __float_as_uint(m));  // p>0: bits monotone
    }
  }
}

__global__ __launch_bounds__(256) void reduce_kernel(
    const float* __restrict__ ssumG, const unsigned int* __restrict__ pmaxG,
    const float* __restrict__ pdiagG, float* __restrict__ out) {
  int i = blockIdx.x * 256 + threadIdx.x;  // row 0..65535
  float pd = pdiagG[i];
  float lossr = __logf(ssumG[i] / pd);
  float corr = (pd >= __uint_as_float(pmaxG[i])) ? 1.f : 0.f;
#pragma unroll
  for (int off = 32; off; off >>= 1) {
    lossr += __shfl_xor(lossr, off, 64);
    corr += __shfl_xor(corr, off, 64);
  }
  __shared__ float pl[4], pc[4];
  int wave = threadIdx.x >> 6, lane = threadIdx.x & 63;
  if (lane == 0) { pl[wave] = lossr; pc[wave] = corr; }
  __syncthreads();
  if (threadIdx.x == 0) {
    const float inv = 1.f / (float)(NS * NU);
    atomicAdd(&out[0], (pl[0] + pl[1] + pl[2] + pl[3]) * inv);
    atomicAdd(&out[1], (pc[0] + pc[1] + pc[2] + pc[3]) * inv);
  }
}

extern "C" void kernel_launch(void* const* d_in, const int* in_sizes, int n_in,
                              void* d_out, int out_size, void* d_ws,
                              size_t ws_size, hipStream_t stream) {
  const float* embeds = (const float*)d_in[0];
  const float* w = (const float*)d_in[1];
  const float* b = (const float*)d_in[2];
  float* out = (float*)d_out;
  char* ws = (char*)d_ws;
  unsigned int* Cb = (unsigned int*)ws;                     // 256 KB fp8
  unsigned int* pmaxG = (unsigned int*)(ws + (256 << 10));  // 256 KB
  float* ssumG = (float*)(ws + (512 << 10));                // 256 KB
  float* pdiagG = (float*)(ws + (768 << 10));               // 256 KB
  float* normsum = (float*)(ws + (1024 << 10));             // 4 KB
  unsigned long long* Ab =
      (unsigned long long*)(ws + (1056 << 10));             // 16 MB fp8 A-frags

  centroid_kernel<<<NS, 256, 0, stream>>>(embeds, Cb, Ab, normsum, ssumG,
                                          pmaxG, out);
  main_kernel<<<1024, 256, 0, stream>>>((const long*)Ab, (const long*)Cb,
                                        normsum, w, b, ssumG, pmaxG, pdiagG);
  reduce_kernel<<<NS * NU / 256, 256, 0, stream>>>(ssumG, pmaxG, pdiagG, out);
}

// Round 10
// 149.735 us; speedup vs baseline: 1.0143x; 1.0143x over previous
//
#include <hip/hip_runtime.h>
#include <math.h>

#define NS 1024   // speakers
#define NU 64     // utterances per speaker
#define NE 256    // embedding dim

typedef __attribute__((ext_vector_type(4))) float f32x4;
typedef __attribute__((ext_vector_type(16))) float f32x16;
typedef long i64x2 __attribute__((ext_vector_type(2)));  // 16B fragment pair

// pack 4 floats -> 4 fp8 e4m3 bytes (HW cvt, OCP on gfx950)
__device__ static inline unsigned int pk4_fp8(float a, float b, float c,
                                              float d) {
  int r = 0;
  r = __builtin_amdgcn_cvt_pk_fp8_f32(a, b, r, false);  // bytes 0,1
  r = __builtin_amdgcn_cvt_pk_fp8_f32(c, d, r, true);   // bytes 2,3
  return (unsigned int)r;
}

// ws layout (bytes):
//   Cb     @ 0     : 1024 cols x 256 k fp8 (256 KB), 32x32-B-frag-permuted
//   pmaxG  @ 256K  : 65536 u32 (256 KB)  float bits of max p per row
//   ssumG  @ 512K  : 65536 f32 (256 KB)  sum of exp(l-M0) per row
//   pdiagG @ 768K  : 65536 f32 (256 KB)  exp(l_gt-M0) per row
//   normsum@ 1024K : 1024 f32 (4 KB)
//   (v10: Ab intermediate ELIMINATED — main builds A-frags from embeds f32)
//
// NOTE: embeds rows are L2-normalized by the reference setup -> ||e||^2 = 1.
//
// Fragment layout for mfma_f32_32x32x16_fp8_fp8 (verified passing in v9):
// 32-wide tile rt, k-step s (=k>>4, 0..15), lane l:
//   row/col = l&31, k-byte = s*16 + (l>>5)*8 + j (j=0..7 within the u64).

__global__ __launch_bounds__(256) void centroid_kernel(
    const float* __restrict__ embeds, unsigned int* __restrict__ Cb,
    float* __restrict__ normsum, float* __restrict__ ssumG,
    unsigned int* __restrict__ pmaxG, float* __restrict__ out) {
  int k = blockIdx.x;   // speaker
  int t = threadIdx.x;
  // zero the per-row accumulators (ws re-poisoned every launch)
  if (t < 64) {
    ssumG[k * 64 + t] = 0.f;
    pmaxG[k * 64 + t] = 0u;
  }
  int wave = t >> 6, e4 = t & 63;

  // ---- per-speaker sum -> normalized centroid (Cb, fp8) ----
  const float4* base =
      (const float4*)(embeds + (size_t)k * NU * NE) + wave * 16 * 64 + e4;
  float4 s = {0.f, 0.f, 0.f, 0.f};
#pragma unroll
  for (int i = 0; i < 16; ++i) {
    float4 v = base[i * 64];
    s.x += v.x; s.y += v.y; s.z += v.z; s.w += v.w;
  }
  __shared__ float4 ps[4][64];
  ps[wave][e4] = s;
  __syncthreads();
  if (t < 64) {
    float4 a = ps[0][t], b = ps[1][t], c = ps[2][t], d = ps[3][t];
    float4 s4;
    s4.x = a.x + b.x + c.x + d.x;
    s4.y = a.y + b.y + c.y + d.y;
    s4.z = a.z + b.z + c.z + d.z;
    s4.w = a.w + b.w + c.w + d.w;
    float sq = s4.x * s4.x + s4.y * s4.y + s4.z * s4.z + s4.w * s4.w;
#pragma unroll
    for (int off = 32; off; off >>= 1) sq += __shfl_xor(sq, off, 64);
    float nrm = sqrtf(sq);
    float inv = 1.f / nrm;
    unsigned int v = pk4_fp8(s4.x * inv, s4.y * inv, s4.z * inv, s4.w * inv);
    // 32x32-B layout (v9-verified): thread t holds centroid bytes 4t..4t+3
    int lane_ = (k & 31) + 32 * ((t >> 1) & 1);
    int idx = (k >> 5) * 2048 + (t >> 3) * 256 + lane_ * 4 +
              (((t >> 2) & 1) << 1) + (t & 1);
    Cb[idx] = v;
    if (t == 0) {
      normsum[k] = nrm;
      if (k == 0) { out[0] = 0.f; out[1] = 0.f; }
    }
  }
}

// Barrier-free fp8 main v10. r0-r9: ~44-46us invariant vs occupancy, B-path,
// prefetch depth, MFMA shape, exp2 cost — instruction-stream levers are all
// null. v10 takes the certain gains + the one untested stall mechanism:
// (1) A-fragments built in-register from embeds f32 (Ab intermediate and its
//     16MB HBM round-trip eliminated; centroid becomes pure-BW ~11us);
// (2) per-block column-tile ROTATION de-phases co-resident blocks' load
//     windows (sums commutative; diag logic per-tile unchanged).
__global__ __launch_bounds__(256) void main_kernel(
    const float* __restrict__ embeds, const long* __restrict__ Cb,
    const float* __restrict__ normsum, const float* __restrict__ wp,
    const float* __restrict__ bp, float* __restrict__ ssumG,
    unsigned int* __restrict__ pmaxG, float* __restrict__ pdiagG) {
  int t = threadIdx.x;
  int wave = t >> 6, lane = t & 63;
  int hi = lane >> 5;
  int b = blockIdx.x;               // 0..1023
  int rg = b >> 1;                  // row group 0..511 (128 rows each)
  int h = b & 1;                    // column half: cols [h*512, +512)
  int jspk = rg * 2 + (wave >> 1);  // this wave's speaker (diag column)
  int r0 = rg * 128 + wave * 32;    // global row base for this wave

  float w = *wp, bia = *bp;
  const float L2E = 1.4426950408889634f;
  float M0 = fabsf(w) + bia;        // >= any logit (cosines in [-1,1])
  float wl = w * L2E;               // p = 2^(d*wl + cl) = exp(l - M0)
  float cl = (bia - M0) * L2E;
  float ns = normsum[jspk];

  const i64x2* Bv = (const i64x2*)Cb;
  int gt_base = h * 16;             // global 32-col tile base
  int start = (b * 5) & 15;         // per-block tile rotation (de-phase)

  // ---- A fragments in-register from embeds f32 (32 rows x 256 k) ----
  // lane owns row r0+(lane&31); u64 for k-step s covers k = s*16+(hi*8)..+8
  long af[16];
  {
    const float* rowp = embeds + (size_t)(r0 + (lane & 31)) * NE + hi * 8;
#pragma unroll
    for (int s = 0; s < 16; ++s) {
      float4 x = *(const float4*)(rowp + s * 16);
      float4 y = *(const float4*)(rowp + s * 16 + 4);
      unsigned int lo = pk4_fp8(x.x, x.y, x.z, x.w);
      unsigned int hh = pk4_fp8(y.x, y.y, y.z, y.w);
      af[s] = (long)(((unsigned long long)hh << 32) | lo);
    }
  }

  // ---- per-lane softmax state: 16 rows (one col each) ----
  float ssum[16], pm[16];
#pragma unroll
  for (int i = 0; i < 16; ++i) {
    ssum[i] = 0.f;
    pm[i] = 0.f;  // p > 0 always
  }

  // B loads: 4 dwordx4 per K-half per 32-col tile (tile index ct, rotated)
  auto loadBA = [&](i64x2 (&BF)[4], int ct) {  // sp 0..3 (k 0..127)
    int cb = (gt_base + ct) * 512 + lane;
#pragma unroll
    for (int sp = 0; sp < 4; ++sp) BF[sp] = Bv[cb + sp * 64];
  };
  auto loadBB = [&](i64x2 (&BF)[4], int ct) {  // sp 4..7 (k 128..255)
    int cb = (gt_base + ct) * 512 + lane + 256;
#pragma unroll
    for (int i = 0; i < 4; ++i) BF[i] = Bv[cb + i * 64];
  };

  // one 32-col tile: 16 MFMAs (single chain), refill B for tile nextCt inside
  auto tile = [&](f32x16& ACC, i64x2 (&BA)[4], i64x2 (&BB)[4], int nextCt) {
    f32x16 a;
#pragma unroll
    for (int i = 0; i < 16; ++i) a[i] = 0.f;
#pragma unroll
    for (int sp = 0; sp < 4; ++sp) {
      a = __builtin_amdgcn_mfma_f32_32x32x16_fp8_fp8(af[2 * sp], BA[sp].x, a,
                                                     0, 0, 0);
      a = __builtin_amdgcn_mfma_f32_32x32x16_fp8_fp8(af[2 * sp + 1], BA[sp].y,
                                                     a, 0, 0, 0);
    }
    loadBA(BA, nextCt);
#pragma unroll
    for (int sp = 0; sp < 4; ++sp) {
      a = __builtin_amdgcn_mfma_f32_32x32x16_fp8_fp8(af[8 + 2 * sp], BB[sp].x,
                                                     a, 0, 0, 0);
      a = __builtin_amdgcn_mfma_f32_32x32x16_fp8_fp8(af[9 + 2 * sp], BB[sp].y,
                                                     a, 0, 0, 0);
    }
    loadBB(BB, nextCt);
    ACC = a;
  };

  // softmax epilogue for 32-col tile ct. C/D layout (verified m74/m101):
  // col = lane&31, row = (reg&3) + 8*(reg>>2) + 4*(lane>>5).
  auto epilogue = [&](f32x16& ACC, int ct) {
    int gt = gt_base + ct;
    bool diagstep = ((jspk >> 5) == gt);  // wave-uniform
    f32x16 a = ACC;
    if (diagstep && (lane & 31) == (jspk & 31)) {
#pragma unroll
      for (int i = 0; i < 16; ++i) {
        float Sv = a[i] * ns;  // e . sum_j  (||e||^2 = 1 by construction)
        float den = fmaxf(fmaf(ns, ns, 1.f) - 2.f * Sv, 1e-30f);
        float val = (Sv - 1.f) * __frsqrt_rn(den);
        float pd = __builtin_amdgcn_exp2f(fmaf(val, wl, cl));  // == epilogue p
        pdiagG[r0 + (i & 3) + 8 * (i >> 2) + 4 * hi] = pd;
        a[i] = val;
      }
    }
#pragma unroll
    for (int i = 0; i < 16; ++i) {
      float p = __builtin_amdgcn_exp2f(fmaf(a[i], wl, cl));  // exp(l - M0)
      ssum[i] += p;
      pm[i] = fmaxf(pm[i], p);
    }
  };

  // ---- rotated pipelined loop over 16 col-tiles, ping-pong epilogue ----
  auto ct = [&](int i) { return (start + i) & 15; };
  i64x2 BA[4], BB[4];
  f32x16 accA, accB;
  loadBA(BA, ct(0));
  loadBB(BB, ct(0));
  tile(accA, BA, BB, ct(1));  // tile 0, refill -> 1
#pragma unroll 1
  for (int T = 1; T < 15; T += 2) {
    tile(accB, BA, BB, ct(T + 1));  // tile T, refill -> T+1
    epilogue(accA, ct(T - 1));
    tile(accA, BA, BB, ct(T + 2 < 16 ? T + 2 : 15));  // tile T+1
    epilogue(accB, ct(T));
  }
  tile(accB, BA, BB, ct(15));  // tile 15 (refill dup, unconsumed)
  epilogue(accA, ct(14));
  epilogue(accB, ct(15));

  // ---- cross-lane reduce over the 32 cols (lanes within each half) ----
#pragma unroll
  for (int i = 0; i < 16; ++i) {
    float s = ssum[i];
    s += __shfl_xor(s, 1, 64);
    s += __shfl_xor(s, 2, 64);
    s += __shfl_xor(s, 4, 64);
    s += __shfl_xor(s, 8, 64);
    s += __shfl_xor(s, 16, 64);
    float m = pm[i];
    m = fmaxf(m, __shfl_xor(m, 1, 64));
    m = fmaxf(m, __shfl_xor(m, 2, 64));
    m = fmaxf(m, __shfl_xor(m, 4, 64));
    m = fmaxf(m, __shfl_xor(m, 8, 64));
    m = fmaxf(m, __shfl_xor(m, 16, 64));
    if ((lane & 31) == 0) {
      int row = r0 + (i & 3) + 8 * (i >> 2) + 4 * hi;
      atomicAdd(&ssumG[row], s);
      atomicMax(&pmaxG[row], __float_as_uint(m));  // p>0: bits monotone
    }
  }
}

__global__ __launch_bounds__(256) void reduce_kernel(
    const float* __restrict__ ssumG, const unsigned int* __restrict__ pmaxG,
    const float* __restrict__ pdiagG, float* __restrict__ out) {
  int i = blockIdx.x * 256 + threadIdx.x;  // row 0..65535
  float pd = pdiagG[i];
  float lossr = __logf(ssumG[i] / pd);
  float corr = (pd >= __uint_as_float(pmaxG[i])) ? 1.f : 0.f;
#pragma unroll
  for (int off = 32; off; off >>= 1) {
    lossr += __shfl_xor(lossr, off, 64);
    corr += __shfl_xor(corr, off, 64);
  }
  __shared__ float pl[4], pc[4];
  int wave = threadIdx.x >> 6, lane = threadIdx.x & 63;
  if (lane == 0) { pl[wave] = lossr; pc[wave] = corr; }
  __syncthreads();
  if (threadIdx.x == 0) {
    const float inv = 1.f / (float)(NS * NU);
    atomicAdd(&out[0], (pl[0] + pl[1] + pl[2] + pl[3]) * inv);
    atomicAdd(&out[1], (pc[0] + pc[1] + pc[2] + pc[3]) * inv);
  }
}

extern "C" void kernel_launch(void* const* d_in, const int* in_sizes, int n_in,
                              void* d_out, int out_size, void* d_ws,
                              size_t ws_size, hipStream_t stream) {
  const float* embeds = (const float*)d_in[0];
  const float* w = (const float*)d_in[1];
  const float* b = (const float*)d_in[2];
  float* out = (float*)d_out;
  char* ws = (char*)d_ws;
  unsigned int* Cb = (unsigned int*)ws;                     // 256 KB fp8
  unsigned int* pmaxG = (unsigned int*)(ws + (256 << 10));  // 256 KB
  float* ssumG = (float*)(ws + (512 << 10));                // 256 KB
  float* pdiagG = (float*)(ws + (768 << 10));               // 256 KB
  float* normsum = (float*)(ws + (1024 << 10));             // 4 KB

  centroid_kernel<<<NS, 256, 0, stream>>>(embeds, Cb, normsum, ssumG, pmaxG,
                                          out);
  main_kernel<<<1024, 256, 0, stream>>>(embeds, (const long*)Cb, normsum, w, b,
                                        ssumG, pmaxG, pdiagG);
  reduce_kernel<<<NS * NU / 256, 256, 0, stream>>>(ssumG, pmaxG, pdiagG, out);
}

// Round 11
// 143.116 us; speedup vs baseline: 1.0612x; 1.0462x over previous
//
#include <hip/hip_runtime.h>
#include <math.h>

#define NS 1024   // speakers
#define NU 64     // utterances per speaker
#define NE 256    // embedding dim

typedef __attribute__((ext_vector_type(4))) float f32x4;
typedef long i64x2 __attribute__((ext_vector_type(2)));  // 16B fragment pair

// pack 4 floats -> 4 fp8 e4m3 bytes (HW cvt, OCP on gfx950)
__device__ static inline unsigned int pk4_fp8(float a, float b, float c,
                                              float d) {
  int r = 0;
  r = __builtin_amdgcn_cvt_pk_fp8_f32(a, b, r, false);  // bytes 0,1
  r = __builtin_amdgcn_cvt_pk_fp8_f32(c, d, r, true);   // bytes 2,3
  return (unsigned int)r;
}

// ws layout (bytes):
//   Cb     @ 0     : 1024 cols x 256 k fp8 (256 KB), MFMA-B-frag-permuted
//   pmaxG  @ 256K  : 65536 u32 (256 KB)  float bits of max p per row
//   ssumG  @ 512K  : 65536 f32 (256 KB)  sum of exp(l-M0) per row
//   pdiagG @ 768K  : 65536 f32 (256 KB)  exp(l_gt-M0) per row
//   normsum@ 1024K : 1024 f32 (4 KB)
//   Ab     @ 1056K : 65536 rows x 256 k fp8 (16 MB), MFMA-A-frag-permuted
//
// NOTE: embeds rows are L2-normalized by the reference setup -> ||e||^2 = 1.
//
// Fragment layout (A and B identical), PAIRED for dwordx4 loads:
// for 16-wide tile index rt (=row>>4 or col>>4), k-step s (=k>>5, 0..7),
// lane = (k>>3 & 3)*16 + (idx&15):
//   u64 frag(rt, s, lane) = buf64[rt*512 + (s>>1)*128 + lane*2 + (s&1)]
// i.e. one i64x2 at [rt*256 + (s>>1)*64 + lane] holds k-steps {2q, 2q+1}.

__global__ __launch_bounds__(256) void centroid_kernel(
    const float* __restrict__ embeds, unsigned int* __restrict__ Cb,
    unsigned long long* __restrict__ Ab, float* __restrict__ normsum,
    float* __restrict__ ssumG, unsigned int* __restrict__ pmaxG,
    float* __restrict__ out) {
  int k = blockIdx.x;   // speaker
  int t = threadIdx.x;
  // zero the per-row accumulators (ws re-poisoned every launch)
  if (t < 64) {
    ssumG[k * 64 + t] = 0.f;
    pmaxG[k * 64 + t] = 0u;
  }
  int wave = t >> 6, e4 = t & 63;

  // ---- phase A: per-speaker sum -> normalized centroid (Cb, fp8) ----
  const float4* base =
      (const float4*)(embeds + (size_t)k * NU * NE) + wave * 16 * 64 + e4;
  float4 s = {0.f, 0.f, 0.f, 0.f};
#pragma unroll
  for (int i = 0; i < 16; ++i) {
    float4 v = base[i * 64];
    s.x += v.x; s.y += v.y; s.z += v.z; s.w += v.w;
  }
  __shared__ float4 ps[4][64];
  ps[wave][e4] = s;
  __syncthreads();
  if (t < 64) {
    float4 a = ps[0][t], b = ps[1][t], c = ps[2][t], d = ps[3][t];
    float4 s4;
    s4.x = a.x + b.x + c.x + d.x;
    s4.y = a.y + b.y + c.y + d.y;
    s4.z = a.z + b.z + c.z + d.z;
    s4.w = a.w + b.w + c.w + d.w;
    float sq = s4.x * s4.x + s4.y * s4.y + s4.z * s4.z + s4.w * s4.w;
#pragma unroll
    for (int off = 32; off; off >>= 1) sq += __shfl_xor(sq, off, 64);
    float nrm = sqrtf(sq);
    float inv = 1.f / nrm;
    unsigned int v = pk4_fp8(s4.x * inv, s4.y * inv, s4.z * inv, s4.w * inv);
    // paired layout: s_=t>>3 (k-step), lane_=((t>>1)&3)*16+(k&15), w_=t&1
    int lane_ = (((t >> 1) & 3) * 16 + (k & 15));
    int idx = (k >> 4) * 1024 + (t >> 4) * 256 + lane_ * 4 +
              (((t >> 3) & 1) << 1) + (t & 1);
    Cb[idx] = v;
    if (t == 0) {
      normsum[k] = nrm;
      if (k == 0) { out[0] = 0.f; out[1] = 0.f; }
    }
  }

  // ---- phase B: fp8 A-fragments for this speaker's 64 rows (L1/L2 warm) ----
  {
    int tile = t >> 6;  // row tile 0..3 within speaker (wave-uniform)
    int l = t & 63;
    int m = l & 15, qq = l >> 4;
    const float* rowp = embeds + (size_t)(k * 64 + tile * 16 + m) * NE;
    i64x2* Ab2 = (i64x2*)Ab;
    size_t base2 = ((size_t)k * 4 + tile) * 256 + l;  // i64x2 units
#pragma unroll
    for (int s2 = 0; s2 < 4; ++s2) {
      // k-steps 2*s2 and 2*s2+1 for this lane, packed as one 16B store
      unsigned long long u[2];
#pragma unroll
      for (int half = 0; half < 2; ++half) {
        int sI = 2 * s2 + half;
        int k0 = sI * 32 + qq * 8;
        float4 x = *(const float4*)(rowp + k0);
        float4 y = *(const float4*)(rowp + k0 + 4);
        unsigned int lo = pk4_fp8(x.x, x.y, x.z, x.w);
        unsigned int hi = pk4_fp8(y.x, y.y, y.z, y.w);
        u[half] = ((unsigned long long)hi << 32) | lo;
      }
      i64x2 v;
      v.x = (long)u[0];
      v.y = (long)u[1];
      Ab2[base2 + s2 * 64] = v;
    }
  }
}

// Barrier-free fp8 main v11: 64 ROWS PER WAVE (wave = one speaker, 4 m-tiles).
// r0-r10: main ~44us invariant across occupancy/B-path/prefetch/MFMA-shape/
// exp-cost; every config had R(rows/wave) in {16,32} => per-CU vmem instr
// count ~constant (~65536/R B-loads/CU). Surviving theory: per-CU vector-mem
// ISSUE/address bandwidth is the shared wall (~70K cyc of addresser time at
// wave64 addressing). v11 halves per-CU vmem instrs (B amortized over 4
// m-tiles): grid 512 (2 blocks/CU), ~175 VGPR -> 2 waves/SIMD. v3 skeleton
// otherwise + v9-verified raw exp2.
__global__ __launch_bounds__(256) void main_kernel(
    const long* __restrict__ Ab, const long* __restrict__ Cb,
    const float* __restrict__ normsum, const float* __restrict__ wp,
    const float* __restrict__ bp, float* __restrict__ ssumG,
    unsigned int* __restrict__ pmaxG, float* __restrict__ pdiagG) {
  int t = threadIdx.x;
  int wave = t >> 6, lane = t & 63;
  int c = lane & 15, q = lane >> 4;
  int b = blockIdx.x;               // 0..511
  int rg = b >> 1;                  // speaker group 0..255 (4 speakers each)
  int h = b & 1;                    // column half: cols [h*512, +512)
  int jspk = rg * 4 + wave;         // this wave's speaker (diag column)
  int r0 = jspk * 64;               // global row base for this wave

  float w = *wp, bia = *bp;
  const float L2E = 1.4426950408889634f;
  float M0 = fabsf(w) + bia;        // >= any logit (cosines in [-1,1])
  float wl = w * L2E;               // p = 2^(d*wl + cl) = exp(l - M0)
  float cl = (bia - M0) * L2E;
  float ns = normsum[jspk];

  const i64x2* Av = (const i64x2*)Ab;
  const i64x2* Bv = (const i64x2*)Cb;

  // ---- A fragments: 16 dwordx4 loads (4 m-tiles = 64 rows) ----
  long af[4][8];
#pragma unroll
  for (int mt = 0; mt < 4; ++mt) {
    int ab2 = ((r0 >> 4) + mt) * 256 + lane;
#pragma unroll
    for (int s2 = 0; s2 < 4; ++s2) {
      i64x2 v = Av[ab2 + s2 * 64];
      af[mt][2 * s2] = v.x;
      af[mt][2 * s2 + 1] = v.y;
    }
  }

  // ---- per-lane softmax state (4 mtiles x 4 regs = 16 row-slots) ----
  float ssum[4][4];
  float pm[4][4];
#pragma unroll
  for (int mt = 0; mt < 4; ++mt)
#pragma unroll
    for (int r = 0; r < 4; ++r) {
      ssum[mt][r] = 0.f;
      pm[mt][r] = 0.f;  // p > 0 always
    }

  // B prefetch: 4 dwordx4 per 16-col tile (shared by all 4 m-tiles)
  auto prefetch = [&](i64x2 (&BF)[4], int Tt) {
    int cb = (h * 32 + Tt) * 256 + lane;
#pragma unroll
    for (int s2 = 0; s2 < 4; ++s2) BF[s2] = Bv[cb + s2 * 64];
  };

  // one column tile: 32 MFMAs, 4 independent chains (one per m-tile)
  auto tile = [&](f32x4 (&ACC)[4], const i64x2 (&BF)[4]) {
#pragma unroll
    for (int mt = 0; mt < 4; ++mt) ACC[mt] = (f32x4){0.f, 0.f, 0.f, 0.f};
#pragma unroll
    for (int s2 = 0; s2 < 4; ++s2) {
#pragma unroll
      for (int mt = 0; mt < 4; ++mt)
        ACC[mt] = __builtin_amdgcn_mfma_f32_16x16x32_fp8_fp8(
            af[mt][2 * s2], BF[s2].x, ACC[mt], 0, 0, 0);
#pragma unroll
      for (int mt = 0; mt < 4; ++mt)
        ACC[mt] = __builtin_amdgcn_mfma_f32_16x16x32_fp8_fp8(
            af[mt][2 * s2 + 1], BF[s2].y, ACC[mt], 0, 0, 0);
    }
  };

  // softmax epilogue for the tile with column-tile index Tt (within half h)
  auto epilogue = [&](f32x4 (&ACC)[4], int Tt) {
    int gt = h * 32 + Tt;
    bool diagstep = ((jspk >> 4) == gt);  // wave-uniform
#pragma unroll
    for (int mt = 0; mt < 4; ++mt) {
      f32x4 a = ACC[mt];
      if (diagstep && c == (jspk & 15)) {
#pragma unroll
        for (int r = 0; r < 4; ++r) {
          float Sv = a[r] * ns;  // e . sum_j  (||e||^2 = 1 by construction)
          float den = fmaxf(fmaf(ns, ns, 1.f) - 2.f * Sv, 1e-30f);
          float val = (Sv - 1.f) * __frsqrt_rn(den);
          float pd = __builtin_amdgcn_exp2f(fmaf(val, wl, cl));
          pdiagG[r0 + mt * 16 + q * 4 + r] = pd;
          a[r] = val;
        }
      }
#pragma unroll
      for (int r = 0; r < 4; ++r) {
        float p = __builtin_amdgcn_exp2f(fmaf(a[r], wl, cl));  // exp(l-M0)
        ssum[mt][r] += p;
        pm[mt][r] = fmaxf(pm[mt][r], p);
      }
    }
  };

  // ---- software-pipelined loop: epilogue(T-1) overlaps MFMA drain of T ----
  i64x2 bf0[4], bf1[4];
  f32x4 accA[4], accB[4];
  prefetch(bf0, 0);
  prefetch(bf1, 1);
  tile(accA, bf0);  // tile 0
#pragma unroll 1
  for (int T = 1; T < 31; T += 2) {
    prefetch(bf0, T + 1);
    tile(accB, bf1);       // tile T
    epilogue(accA, T - 1);
    prefetch(bf1, T + 2);
    tile(accA, bf0);       // tile T+1
    epilogue(accB, T);
  }
  tile(accB, bf1);         // tile 31
  epilogue(accA, 30);
  epilogue(accB, 31);

  // ---- cross-lane (16 column-lanes) reduce, then global atomic combine ----
#pragma unroll
  for (int mt = 0; mt < 4; ++mt)
#pragma unroll
    for (int r = 0; r < 4; ++r) {
      float s = ssum[mt][r];
      s += __shfl_xor(s, 1, 64);
      s += __shfl_xor(s, 2, 64);
      s += __shfl_xor(s, 4, 64);
      s += __shfl_xor(s, 8, 64);
      float m = pm[mt][r];
      m = fmaxf(m, __shfl_xor(m, 1, 64));
      m = fmaxf(m, __shfl_xor(m, 2, 64));
      m = fmaxf(m, __shfl_xor(m, 4, 64));
      m = fmaxf(m, __shfl_xor(m, 8, 64));
      if (c == 0) {
        int row = r0 + mt * 16 + q * 4 + r;
        atomicAdd(&ssumG[row], s);
        atomicMax(&pmaxG[row], __float_as_uint(m));  // p>0: bits monotone
      }
    }
}

__global__ __launch_bounds__(256) void reduce_kernel(
    const float* __restrict__ ssumG, const unsigned int* __restrict__ pmaxG,
    const float* __restrict__ pdiagG, float* __restrict__ out) {
  int i = blockIdx.x * 256 + threadIdx.x;  // row 0..65535
  float pd = pdiagG[i];
  float lossr = __logf(ssumG[i] / pd);
  float corr = (pd >= __uint_as_float(pmaxG[i])) ? 1.f : 0.f;
#pragma unroll
  for (int off = 32; off; off >>= 1) {
    lossr += __shfl_xor(lossr, off, 64);
    corr += __shfl_xor(corr, off, 64);
  }
  __shared__ float pl[4], pc[4];
  int wave = threadIdx.x >> 6, lane = threadIdx.x & 63;
  if (lane == 0) { pl[wave] = lossr; pc[wave] = corr; }
  __syncthreads();
  if (threadIdx.x == 0) {
    const float inv = 1.f / (float)(NS * NU);
    atomicAdd(&out[0], (pl[0] + pl[1] + pl[2] + pl[3]) * inv);
    atomicAdd(&out[1], (pc[0] + pc[1] + pc[2] + pc[3]) * inv);
  }
}

extern "C" void kernel_launch(void* const* d_in, const int* in_sizes, int n_in,
                              void* d_out, int out_size, void* d_ws,
                              size_t ws_size, hipStream_t stream) {
  const float* embeds = (const float*)d_in[0];
  const float* w = (const float*)d_in[1];
  const float* b = (const float*)d_in[2];
  float* out = (float*)d_out;
  char* ws = (char*)d_ws;
  unsigned int* Cb = (unsigned int*)ws;                     // 256 KB fp8
  unsigned int* pmaxG = (unsigned int*)(ws + (256 << 10));  // 256 KB
  float* ssumG = (float*)(ws + (512 << 10));                // 256 KB
  float* pdiagG = (float*)(ws + (768 << 10));               // 256 KB
  float* normsum = (float*)(ws + (1024 << 10));             // 4 KB
  unsigned long long* Ab =
      (unsigned long long*)(ws + (1056 << 10));             // 16 MB fp8 A-frags

  centroid_kernel<<<NS, 256, 0, stream>>>(embeds, Cb, Ab, normsum, ssumG,
                                          pmaxG, out);
  main_kernel<<<512, 256, 0, stream>>>((const long*)Ab, (const long*)Cb,
                                       normsum, w, b, ssumG, pmaxG, pdiagG);
  reduce_kernel<<<NS * NU / 256, 256, 0, stream>>>(ssumG, pmaxG, pdiagG, out);
}